// Round 1
// baseline (423.362 us; speedup 1.0000x reference)
//
#include <hip/hip_runtime.h>
#include <hip/hip_bf16.h>
#include <type_traits>

#define T_LEN 2048
#define HN 32
#define KVHN 8
#define DH 64

typedef unsigned short u16;
typedef unsigned int u32;
typedef __attribute__((ext_vector_type(8))) short bf16x8;
typedef __attribute__((ext_vector_type(4))) float f32x4;

__device__ __forceinline__ u16 f2b(float f) {
  __hip_bfloat16 h = __float2bfloat16(f);
  return __builtin_bit_cast(u16, h);
}
__device__ __forceinline__ float b2f(u16 u) {
  return __bfloat162float(__builtin_bit_cast(__hip_bfloat16, u));
}

__device__ __forceinline__ void gload_lds16(const void* g, void* l) {
  __builtin_amdgcn_global_load_lds(
      (const __attribute__((address_space(1))) u32*)g,
      (__attribute__((address_space(3))) u32*)l, 16, 0, 0);
}

// ---------------- fp32 -> bf16 convert (8 elems/thread) ----------------
__global__ __launch_bounds__(256) void cvt_f32_bf16(const float* __restrict__ in,
                                                    u16* __restrict__ out, int n8) {
  int i = blockIdx.x * 256 + threadIdx.x;
  if (i >= n8) return;
  float4 a = ((const float4*)in)[i * 2];
  float4 b = ((const float4*)in)[i * 2 + 1];
  union { u16 s[8]; uint4 v; } r;
  r.s[0] = f2b(a.x); r.s[1] = f2b(a.y); r.s[2] = f2b(a.z); r.s[3] = f2b(a.w);
  r.s[4] = f2b(b.x); r.s[5] = f2b(b.y); r.s[6] = f2b(b.z); r.s[7] = f2b(b.w);
  ((uint4*)out)[i] = r.v;
}

// ---------------- RoPE (in-place, optional scale folded in) ----------------
// X layout: (B*T, nheads, 64). idx -> (row = bt*nheads + h, d in 0..31)
__global__ __launch_bounds__(256) void rope_scale(u16* __restrict__ X,
                                                  const float* __restrict__ cosT,
                                                  const float* __restrict__ sinT,
                                                  int hlog, float mul, int total) {
  int idx = blockIdx.x * 256 + threadIdx.x;
  if (idx >= total) return;
  int d = idx & 31;
  int row = idx >> 5;
  int t = (row >> hlog) & (T_LEN - 1);
  float c = cosT[t * DH + d];
  float s = sinT[t * DH + d];
  u16* p = X + (size_t)row * DH;
  float lo = b2f(p[d]), hi = b2f(p[d + 32]);
  p[d]      = f2b((lo * c - hi * s) * mul);
  p[d + 32] = f2b((hi * c + lo * s) * mul);
}

// ---------------- m97-structure bf16 GEMM: C = A @ Bt^T ----------------
// A: [M,K] bf16 row-major, Bt: [N,K] bf16 row-major. 128x128 tile, BK=32.
template <typename OutT>
__device__ __forceinline__ void gemm_bt_core(const u16* __restrict__ A,
                                             const u16* __restrict__ Bt,
                                             OutT* __restrict__ C,
                                             int brow, int bcol, int N, int K,
                                             u16* As, u16* Bs) {
  int tid = threadIdx.x;
  int w = tid >> 6, l = tid & 63;
  int wr = w >> 1, wc = w & 1;
  int lr = tid >> 2, lc = (tid & 3) * 8;
  f32x4 acc[4][4] = {};
  for (int k0 = 0; k0 < K; k0 += 32) {
    __syncthreads();
#pragma unroll
    for (int i = 0; i < 2; ++i) {
      gload_lds16(A + (size_t)(brow + i * 64 + lr) * K + k0 + lc,
                  (char*)As + i * 4096 + w * 1024);
      gload_lds16(Bt + (size_t)(bcol + i * 64 + lr) * K + k0 + lc,
                  (char*)Bs + i * 4096 + w * 1024);
    }
    __syncthreads();
    bf16x8 af[4], bfr[4];
#pragma unroll
    for (int m = 0; m < 4; ++m)
      af[m] = *(const bf16x8*)((const char*)As + (wr * 64 + m * 16 + (l & 15)) * 64 + (l >> 4) * 16);
#pragma unroll
    for (int n = 0; n < 4; ++n)
      bfr[n] = *(const bf16x8*)((const char*)Bs + (wc * 64 + n * 16 + (l & 15)) * 64 + (l >> 4) * 16);
#pragma unroll
    for (int m = 0; m < 4; ++m)
#pragma unroll
      for (int n = 0; n < 4; ++n)
        acc[m][n] = __builtin_amdgcn_mfma_f32_16x16x32_bf16(af[m], bfr[n], acc[m][n], 0, 0, 0);
  }
#pragma unroll
  for (int m = 0; m < 4; ++m)
#pragma unroll
    for (int n = 0; n < 4; ++n)
#pragma unroll
      for (int r = 0; r < 4; ++r) {
        size_t row = brow + wr * 64 + m * 16 + (l >> 4) * 4 + r;
        size_t col = bcol + wc * 64 + n * 16 + (l & 15);
        if constexpr (std::is_same<OutT, float>::value)
          C[row * N + col] = acc[m][n][r];
        else
          C[row * N + col] = f2b(acc[m][n][r]);
      }
}

template <typename OutT>
__global__ __launch_bounds__(256) void gemm_bt(const u16* __restrict__ A,
                                               const u16* __restrict__ Bt,
                                               OutT* __restrict__ C, int N, int K) {
  __shared__ u16 As[128 * 32];
  __shared__ u16 Bs[128 * 32];
  gemm_bt_core<OutT>(A, Bt, C, blockIdx.y * 128, blockIdx.x * 128, N, K, As, Bs);
}

// fused K and V projection (N=512 each); grid.x 0..7: 0-3 -> K, 4-7 -> V
__global__ __launch_bounds__(256) void gemm_kv(const u16* __restrict__ A,
                                               const u16* __restrict__ Wk,
                                               const u16* __restrict__ Wv,
                                               u16* __restrict__ Ko,
                                               u16* __restrict__ Vo, int K) {
  __shared__ u16 As[128 * 32];
  __shared__ u16 Bs[128 * 32];
  int x = blockIdx.x;
  const u16* Bt = (x < 4) ? Wk : Wv;
  u16* C = (x < 4) ? Ko : Vo;
  gemm_bt_core<u16>(A, Bt, C, blockIdx.y * 128, (x & 3) * 128, 512, K, As, Bs);
}

// ---------------- causal flash attention ----------------
// Q: (B,T,HN,DH) bf16 (pre-scaled by 1/8), K/V: (B,T,KVHN,DH) bf16.
// O: (B,T,HN,DH) bf16. grid = (T/64, HN, B), 256 threads (4 waves x 16 q-rows).
__global__ __launch_bounds__(256) void attn_kernel(const u16* __restrict__ Q,
                                                   const u16* __restrict__ K,
                                                   const u16* __restrict__ V,
                                                   u16* __restrict__ O) {
  int qi = blockIdx.x, h = blockIdx.y, b = blockIdx.z;
  int kvh = h >> 2;  // G=4
  int tid = threadIdx.x;
  int w = tid >> 6, l = tid & 63;
  int q0 = qi * 64;

  __shared__ u16 Qs[64 * 64];   // XOR-swizzled rows
  __shared__ u16 Ks[64 * 64];   // XOR-swizzled rows
  __shared__ u16 Ps[4][16 * 64];// per-wave P strip, XOR-swizzled
  __shared__ u32 Vt[64 * 34];   // V^T packed pairs: Vt[d][kv/2], stride 34 u32

  // stage Q (source-swizzled so LDS holds (r, blk^(r&7)))
#pragma unroll
  for (int i = 0; i < 2; ++i) {
    int rr = i * 32 + (tid >> 3);
    int blk = (tid & 7) ^ (rr & 7);
    gload_lds16(Q + ((size_t)((b * T_LEN + q0 + rr) * HN + h)) * DH + blk * 8,
                (char*)Qs + i * 4096 + w * 1024);
  }
  __syncthreads();

  bf16x8 qf[2];
  {
    int R = w * 16 + (l & 15);
#pragma unroll
    for (int kk = 0; kk < 2; ++kk) {
      int kb = (l >> 4) + kk * 4;
      qf[kk] = *(const bf16x8*)((const char*)Qs + R * 128 + ((kb ^ (R & 7)) * 16));
    }
  }

  f32x4 o[4] = {};
  float mx[4], ls[4];
#pragma unroll
  for (int r = 0; r < 4; ++r) { mx[r] = -1e30f; ls[r] = 0.f; }
  const float L2E = 1.4426950408889634f;

  for (int j = 0; j <= qi; ++j) {
    int kv0 = j * 64;
    __syncthreads();  // prior tile's LDS reads done
    // stage K
#pragma unroll
    for (int i = 0; i < 2; ++i) {
      int rr = i * 32 + (tid >> 3);
      int blk = (tid & 7) ^ (rr & 7);
      gload_lds16(K + ((size_t)((b * T_LEN + kv0 + rr) * KVHN + kvh)) * DH + blk * 8,
                  (char*)Ks + i * 4096 + w * 1024);
    }
    // stage V transposed: thread reads 8 d-elems of rows 2*r2, 2*r2+1; packs pairs
    {
      int r2 = tid >> 3;         // 0..31
      int d0 = (tid & 7) * 8;
      const u16* g0 = V + ((size_t)((b * T_LEN + kv0 + 2 * r2) * KVHN + kvh)) * DH + d0;
      uint4 va = *(const uint4*)g0;
      uint4 vb = *(const uint4*)(g0 + KVHN * DH);
      const u16* pa = (const u16*)&va;
      const u16* pb = (const u16*)&vb;
#pragma unroll
      for (int jj = 0; jj < 8; ++jj)
        Vt[(d0 + jj) * 34 + r2] = (u32)pa[jj] | ((u32)pb[jj] << 16);
    }
    __syncthreads();

    // S = Q K^T (this wave's 16 q-rows x 64 keys)
    f32x4 s[4] = {};
#pragma unroll
    for (int kk = 0; kk < 2; ++kk)
#pragma unroll
      for (int n = 0; n < 4; ++n) {
        int R = n * 16 + (l & 15);
        int kb = (l >> 4) + kk * 4;
        bf16x8 kf = *(const bf16x8*)((const char*)Ks + R * 128 + ((kb ^ (R & 7)) * 16));
        s[n] = __builtin_amdgcn_mfma_f32_16x16x32_bf16(qf[kk], kf, s[n], 0, 0, 0);
      }

    if (j == qi) {  // diagonal tile: mask col > row
#pragma unroll
      for (int n = 0; n < 4; ++n)
#pragma unroll
        for (int r = 0; r < 4; ++r) {
          int col = n * 16 + (l & 15);
          int row = w * 16 + (l >> 4) * 4 + r;
          if (col > row) s[n][r] = -1e30f;
        }
    }

    // online softmax (per lane: 4 rows x 4 cols; cross-lane max over 16-group)
#pragma unroll
    for (int r = 0; r < 4; ++r) {
      float rm = fmaxf(fmaxf(s[0][r], s[1][r]), fmaxf(s[2][r], s[3][r]));
      rm = fmaxf(rm, __shfl_xor(rm, 1));
      rm = fmaxf(rm, __shfl_xor(rm, 2));
      rm = fmaxf(rm, __shfl_xor(rm, 4));
      rm = fmaxf(rm, __shfl_xor(rm, 8));
      float nm = fmaxf(mx[r], rm);
      float fac = exp2f((mx[r] - nm) * L2E);
      mx[r] = nm;
      float psum = 0.f;
#pragma unroll
      for (int n = 0; n < 4; ++n) {
        float p = exp2f((s[n][r] - nm) * L2E);
        s[n][r] = p;
        psum += p;
      }
      ls[r] = ls[r] * fac + psum;
#pragma unroll
      for (int n = 0; n < 4; ++n) o[n][r] *= fac;
    }

    // P -> LDS (bf16, swizzled), wave-local strip
#pragma unroll
    for (int n = 0; n < 4; ++n)
#pragma unroll
      for (int r = 0; r < 4; ++r) {
        int row = (l >> 4) * 4 + r;
        int col = n * 16 + (l & 15);
        int blk = (col >> 3) ^ (row & 7);
        *(u16*)((char*)Ps[w] + row * 128 + blk * 16 + (col & 7) * 2) = f2b(s[n][r]);
      }
    __syncthreads();  // cross-lane LDS visibility

    // O += P V
#pragma unroll
    for (int kk = 0; kk < 2; ++kk) {
      int prow = l & 15;
      int pkb = (l >> 4) + kk * 4;
      bf16x8 pf = *(const bf16x8*)((const char*)Ps[w] + prow * 128 + ((pkb ^ (prow & 7)) * 16));
#pragma unroll
      for (int n = 0; n < 4; ++n) {
        int d = n * 16 + (l & 15);
        int kvh2 = ((l >> 4) * 8 + kk * 32) >> 1;
        const u32* vp = &Vt[d * 34 + kvh2];
        union { u32 u[4]; bf16x8 v; } uu;
        uu.u[0] = vp[0]; uu.u[1] = vp[1]; uu.u[2] = vp[2]; uu.u[3] = vp[3];
        o[n] = __builtin_amdgcn_mfma_f32_16x16x32_bf16(pf, uu.v, o[n], 0, 0, 0);
      }
    }
  }

  // normalize + write (B,T,HN,DH)
#pragma unroll
  for (int r = 0; r < 4; ++r) {
    float sum = ls[r];
    sum += __shfl_xor(sum, 1);
    sum += __shfl_xor(sum, 2);
    sum += __shfl_xor(sum, 4);
    sum += __shfl_xor(sum, 8);
    float inv = 1.f / sum;
    int t = q0 + w * 16 + (l >> 4) * 4 + r;
#pragma unroll
    for (int n = 0; n < 4; ++n) {
      int d = n * 16 + (l & 15);
      O[((size_t)(b * T_LEN + t) * HN + h) * DH + d] = f2b(o[n][r] * inv);
    }
  }
}

extern "C" void kernel_launch(void* const* d_in, const int* in_sizes, int n_in,
                              void* d_out, int out_size, void* d_ws, size_t ws_size,
                              hipStream_t stream) {
  const float* x    = (const float*)d_in[0];
  const float* Wq   = (const float*)d_in[1];
  const float* Wk   = (const float*)d_in[2];
  const float* Wv   = (const float*)d_in[3];
  const float* Wo   = (const float*)d_in[4];
  const float* cosT = (const float*)d_in[5];
  const float* sinT = (const float*)d_in[6];

  char* ws = (char*)d_ws;
  u16* xb  = (u16*)(ws + 0);          // 4096x2048       16 MB
  u16* wqb = (u16*)(ws + 16777216);   // 2048x2048        8 MB
  u16* wkb = (u16*)(ws + 25165824);   // 512x2048         2 MB
  u16* wvb = (u16*)(ws + 27262976);   // 512x2048         2 MB
  u16* wob = (u16*)(ws + 29360128);   // 2048x2048        8 MB
  u16* qb  = (u16*)(ws + 37748736);   // (B,T,32,64)     16 MB
  u16* kb  = (u16*)(ws + 54525952);   // (B,T,8,64)       4 MB
  u16* vb  = (u16*)(ws + 58720256);   // (B,T,8,64)       4 MB
  u16* aob = (u16*)(ws + 62914560);   // (B,T,32,64)     16 MB

  cvt_f32_bf16<<<4096, 256, 0, stream>>>(x, xb, 1048576);
  cvt_f32_bf16<<<2048, 256, 0, stream>>>(Wq, wqb, 524288);
  cvt_f32_bf16<<<512, 256, 0, stream>>>(Wk, wkb, 131072);
  cvt_f32_bf16<<<512, 256, 0, stream>>>(Wv, wvb, 131072);
  cvt_f32_bf16<<<2048, 256, 0, stream>>>(Wo, wob, 524288);

  gemm_bt<u16><<<dim3(16, 32), 256, 0, stream>>>(xb, wqb, qb, 2048, 2048);
  gemm_kv<<<dim3(8, 32), 256, 0, stream>>>(xb, wkb, wvb, kb, vb, 2048);

  rope_scale<<<16384, 256, 0, stream>>>(qb, cosT, sinT, 5, 0.125f, 4194304);
  rope_scale<<<4096, 256, 0, stream>>>(kb, cosT, sinT, 3, 1.0f, 1048576);

  attn_kernel<<<dim3(32, 32, 2), 256, 0, stream>>>(qb, kb, vb, aob);

  gemm_bt<float><<<dim3(16, 32), 256, 0, stream>>>(aob, wob, (float*)d_out, 2048, 2048);
}

// Round 2
// 337.329 us; speedup vs baseline: 1.2550x; 1.2550x over previous
//
#include <hip/hip_runtime.h>
#include <hip/hip_bf16.h>
#include <type_traits>

#define T_LEN 2048
#define HN 32
#define KVHN 8
#define DH 64

typedef unsigned short u16;
typedef unsigned int u32;
typedef __attribute__((ext_vector_type(8))) short bf16x8;
typedef __attribute__((ext_vector_type(4))) float f32x4;
typedef __attribute__((ext_vector_type(16))) float f32x16;

__device__ __forceinline__ u16 f2b(float f) {
  __hip_bfloat16 h = __float2bfloat16(f);
  return __builtin_bit_cast(u16, h);
}
__device__ __forceinline__ float b2f(u16 u) {
  return __bfloat162float(__builtin_bit_cast(__hip_bfloat16, u));
}
__device__ __forceinline__ u32 pk2(float a, float b) {
  return (u32)f2b(a) | ((u32)f2b(b) << 16);
}

__device__ __forceinline__ void gload_lds16(const void* g, void* l) {
  __builtin_amdgcn_global_load_lds(
      (const __attribute__((address_space(1))) u32*)g,
      (__attribute__((address_space(3))) u32*)l, 16, 0, 0);
}

// ---------------- fp32 -> bf16 convert (8 elems/thread) ----------------
__global__ __launch_bounds__(256) void cvt_f32_bf16(const float* __restrict__ in,
                                                    u16* __restrict__ out, int n8) {
  int i = blockIdx.x * 256 + threadIdx.x;
  if (i >= n8) return;
  float4 a = ((const float4*)in)[i * 2];
  float4 b = ((const float4*)in)[i * 2 + 1];
  union { u16 s[8]; uint4 v; } r;
  r.s[0] = f2b(a.x); r.s[1] = f2b(a.y); r.s[2] = f2b(a.z); r.s[3] = f2b(a.w);
  r.s[4] = f2b(b.x); r.s[5] = f2b(b.y); r.s[6] = f2b(b.z); r.s[7] = f2b(b.w);
  ((uint4*)out)[i] = r.v;
}

// ---------------- RoPE (in-place, optional scale folded in) ----------------
__global__ __launch_bounds__(256) void rope_scale(u16* __restrict__ X,
                                                  const float* __restrict__ cosT,
                                                  const float* __restrict__ sinT,
                                                  int hlog, float mul, int total) {
  int idx = blockIdx.x * 256 + threadIdx.x;
  if (idx >= total) return;
  int d = idx & 31;
  int row = idx >> 5;
  int t = (row >> hlog) & (T_LEN - 1);
  float c = cosT[t * DH + d];
  float s = sinT[t * DH + d];
  u16* p = X + (size_t)row * DH;
  float lo = b2f(p[d]), hi = b2f(p[d + 32]);
  p[d]      = f2b((lo * c - hi * s) * mul);
  p[d + 32] = f2b((hi * c + lo * s) * mul);
}

// ---------------- m97-structure bf16 GEMM: C = A @ Bt^T ----------------
template <typename OutT>
__device__ __forceinline__ void gemm_bt_core(const u16* __restrict__ A,
                                             const u16* __restrict__ Bt,
                                             OutT* __restrict__ C,
                                             int brow, int bcol, int N, int K,
                                             u16* As, u16* Bs) {
  int tid = threadIdx.x;
  int w = tid >> 6, l = tid & 63;
  int wr = w >> 1, wc = w & 1;
  int lr = tid >> 2, lc = (tid & 3) * 8;
  f32x4 acc[4][4] = {};
  for (int k0 = 0; k0 < K; k0 += 32) {
    __syncthreads();
#pragma unroll
    for (int i = 0; i < 2; ++i) {
      gload_lds16(A + (size_t)(brow + i * 64 + lr) * K + k0 + lc,
                  (char*)As + i * 4096 + w * 1024);
      gload_lds16(Bt + (size_t)(bcol + i * 64 + lr) * K + k0 + lc,
                  (char*)Bs + i * 4096 + w * 1024);
    }
    __syncthreads();
    bf16x8 af[4], bfr[4];
#pragma unroll
    for (int m = 0; m < 4; ++m)
      af[m] = *(const bf16x8*)((const char*)As + (wr * 64 + m * 16 + (l & 15)) * 64 + (l >> 4) * 16);
#pragma unroll
    for (int n = 0; n < 4; ++n)
      bfr[n] = *(const bf16x8*)((const char*)Bs + (wc * 64 + n * 16 + (l & 15)) * 64 + (l >> 4) * 16);
#pragma unroll
    for (int m = 0; m < 4; ++m)
#pragma unroll
      for (int n = 0; n < 4; ++n)
        acc[m][n] = __builtin_amdgcn_mfma_f32_16x16x32_bf16(af[m], bfr[n], acc[m][n], 0, 0, 0);
  }
#pragma unroll
  for (int m = 0; m < 4; ++m)
#pragma unroll
    for (int n = 0; n < 4; ++n)
#pragma unroll
      for (int r = 0; r < 4; ++r) {
        size_t row = brow + wr * 64 + m * 16 + (l >> 4) * 4 + r;
        size_t col = bcol + wc * 64 + n * 16 + (l & 15);
        if constexpr (std::is_same<OutT, float>::value)
          C[row * N + col] = acc[m][n][r];
        else
          C[row * N + col] = f2b(acc[m][n][r]);
      }
}

template <typename OutT>
__global__ __launch_bounds__(256) void gemm_bt(const u16* __restrict__ A,
                                               const u16* __restrict__ Bt,
                                               OutT* __restrict__ C, int N, int K) {
  __shared__ u16 As[128 * 32];
  __shared__ u16 Bs[128 * 32];
  gemm_bt_core<OutT>(A, Bt, C, blockIdx.y * 128, blockIdx.x * 128, N, K, As, Bs);
}

__global__ __launch_bounds__(256) void gemm_kv(const u16* __restrict__ A,
                                               const u16* __restrict__ Wk,
                                               const u16* __restrict__ Wv,
                                               u16* __restrict__ Ko,
                                               u16* __restrict__ Vo, int K) {
  __shared__ u16 As[128 * 32];
  __shared__ u16 Bs[128 * 32];
  int x = blockIdx.x;
  const u16* Bt = (x < 4) ? Wk : Wv;
  u16* C = (x < 4) ? Ko : Vo;
  gemm_bt_core<u16>(A, Bt, C, blockIdx.y * 128, (x & 3) * 128, 512, K, As, Bs);
}

// ---------------- causal flash attention, 32x32 swapped-QK^T ----------------
// Q (pre-scaled 1/8), K, V: (B,T,*,64) bf16. O: (B,T,HN,64) bf16.
// grid = (T/128, HN, B), 256 threads = 4 waves x 32 q-rows.
// LDS: [0,16K) K dbuf (also Q-stage + epilogue); [16K, 16K+17408) Vt pair dbuf.
#define MKFRAG(SS, RB, OUTV)                                              \
  {                                                                       \
    u32 a_ = pk2(SS[RB + 0], SS[RB + 1]);                                 \
    u32 b_ = pk2(SS[RB + 4], SS[RB + 5]);                                 \
    u32 c_ = pk2(SS[RB + 2], SS[RB + 3]);                                 \
    u32 d_ = pk2(SS[RB + 6], SS[RB + 7]);                                 \
    asm volatile("v_permlane32_swap_b32 %0, %1" : "+v"(a_), "+v"(b_));    \
    asm volatile("v_permlane32_swap_b32 %0, %1" : "+v"(c_), "+v"(d_));    \
    union { u32 u[4]; bf16x8 v; } r_;                                     \
    r_.u[0] = a_; r_.u[1] = c_; r_.u[2] = b_; r_.u[3] = d_;               \
    OUTV = r_.v;                                                          \
  }

__global__ __launch_bounds__(256, 3) void attn_kernel(const u16* __restrict__ Q,
                                                      const u16* __restrict__ K,
                                                      const u16* __restrict__ V,
                                                      u16* __restrict__ O) {
  const float L2E = 1.4426950408889634f;
  int qi = blockIdx.x, h = blockIdx.y, b = blockIdx.z;
  int kvh = h >> 2;
  int tid = threadIdx.x;
  int w = tid >> 6, l = tid & 63;
  int lq = l & 31;
  int hi = l >> 5;
  int q0blk = qi * 128;
  int q0w = q0blk + w * 32;
  int nt = 2 * qi + 2;
  const size_t bT = (size_t)b * T_LEN;

  __shared__ char lds[33792];

  // ---- stage Q (swizzled source), read frags, free the region ----
#pragma unroll
  for (int i = 0; i < 4; ++i) {
    int u = (i * 4 + w) * 64 + l;
    int row = u >> 3, blk = (u & 7) ^ (row & 7);
    gload_lds16(Q + ((bT + q0blk + row) * HN + h) * 64 + blk * 8,
                lds + (i * 4 + w) * 1024);
  }
  __syncthreads();
  bf16x8 qf[4];
  {
    int R = w * 32 + lq;
#pragma unroll
    for (int ks = 0; ks < 4; ++ks) {
      int kb = 2 * ks + hi;
      qf[ks] = *(const bf16x8*)(lds + R * 128 + ((kb ^ (R & 7)) * 16));
    }
  }
  __syncthreads();

  // ---- V reg-stage state ----
  int r2 = tid >> 3;            // kv-pair 0..31
  int d0v = (tid & 7) * 8;      // d chunk
  uint4 va, vb;

  // ---- stage tile 0 ----
  {
#pragma unroll
    for (int i = 0; i < 2; ++i) {
      int u = (w * 2 + i) * 64 + l;
      int row = u >> 3, blk = (u & 7) ^ (row & 7);
      gload_lds16(K + ((bT + row) * KVHN + kvh) * 64 + blk * 8,
                  lds + (w * 2 + i) * 1024);
    }
    const u16* g0 = V + ((bT + 2 * r2) * KVHN + kvh) * 64 + d0v;
    va = *(const uint4*)g0;
    vb = *(const uint4*)(g0 + KVHN * 64);
    u32* vt = (u32*)(lds + 16384);
    const u16* pa = (const u16*)&va;
    const u16* pb = (const u16*)&vb;
#pragma unroll
    for (int j = 0; j < 8; ++j)
      vt[(d0v + j) * 34 + r2] = (u32)pa[j] | ((u32)pb[j] << 16);
  }

  f32x16 o0 = {}, o1 = {};
  float mx = -1e30f, ls = 0.f;

  for (int t = 0; t < nt; ++t) {
    __syncthreads();   // staging of buf[t&1] complete; buf[t&1^1] free
    int cur = t & 1, nxt = cur ^ 1;
    bool last = (t + 1 >= nt);
    int kv0 = t * 64;
    bool skip = kv0 > q0w + 31;

    // issue next-tile staging (overlaps with this tile's compute)
    if (!last) {
      int kvn = kv0 + 64;
#pragma unroll
      for (int i = 0; i < 2; ++i) {
        int u = (w * 2 + i) * 64 + l;
        int row = u >> 3, blk = (u & 7) ^ (row & 7);
        gload_lds16(K + ((bT + kvn + row) * KVHN + kvh) * 64 + blk * 8,
                    lds + nxt * 8192 + (w * 2 + i) * 1024);
      }
      const u16* g0 = V + ((bT + kvn + 2 * r2) * KVHN + kvh) * 64 + d0v;
      va = *(const uint4*)g0;
      vb = *(const uint4*)(g0 + KVHN * 64);
    }

    f32x16 s0 = {}, s1 = {};
    if (!skip) {
      const char* kb = lds + cur * 8192;
#pragma unroll
      for (int ks = 0; ks < 4; ++ks) {
        int kbi = 2 * ks + hi;
        int R0 = lq, R1 = 32 + lq;
        bf16x8 k0 = *(const bf16x8*)(kb + R0 * 128 + ((kbi ^ (R0 & 7)) * 16));
        bf16x8 k1 = *(const bf16x8*)(kb + R1 * 128 + ((kbi ^ (R1 & 7)) * 16));
        s0 = __builtin_amdgcn_mfma_f32_32x32x16_bf16(k0, qf[ks], s0, 0, 0, 0);
        s1 = __builtin_amdgcn_mfma_f32_32x32x16_bf16(k1, qf[ks], s1, 0, 0, 0);
      }
      if (kv0 + 63 > q0w) {   // partial tile: causal mask
        int qa = q0w + lq;
#pragma unroll
        for (int r = 0; r < 16; ++r) {
          int kvl = (r & 3) + 8 * (r >> 2) + 4 * hi;
          if (kv0 + kvl > qa) s0[r] = -1e30f;
          if (kv0 + 32 + kvl > qa) s1[r] = -1e30f;
        }
      }
      // online softmax (q = lane&31; kv split across hi-halves)
      float rm = s0[0];
#pragma unroll
      for (int r = 1; r < 16; ++r) rm = fmaxf(rm, s0[r]);
#pragma unroll
      for (int r = 0; r < 16; ++r) rm = fmaxf(rm, s1[r]);
      rm = fmaxf(rm, __shfl_xor(rm, 32));
      float nm = mx;
      if (!__all(rm <= mx + 8.0f)) {   // defer-max (T13)
        nm = fmaxf(mx, rm);
        float fac = exp2f((mx - nm) * L2E);
        mx = nm;
        ls *= fac;
#pragma unroll
        for (int r = 0; r < 16; ++r) { o0[r] *= fac; o1[r] *= fac; }
      }
      float psum = 0.f;
#pragma unroll
      for (int r = 0; r < 16; ++r) { float p = exp2f((s0[r] - nm) * L2E); s0[r] = p; psum += p; }
#pragma unroll
      for (int r = 0; r < 16; ++r) { float p = exp2f((s1[r] - nm) * L2E); s1[r] = p; psum += p; }
      ls += psum;
    }

    // write next-tile V (pair-packed transpose) into the other buffer
    if (!last) {
      u32* vt = (u32*)(lds + 16384 + nxt * 8704);
      const u16* pa = (const u16*)&va;
      const u16* pb = (const u16*)&vb;
#pragma unroll
      for (int j = 0; j < 8; ++j)
        vt[(d0v + j) * 34 + r2] = (u32)pa[j] | ((u32)pb[j] << 16);
    }

    if (!skip) {
      // P fragments (B-operand, in-register via pack+permlane) + PV
      const u32* vt = (const u32*)(lds + 16384 + cur * 8704);
#pragma unroll
      for (int sl = 0; sl < 4; ++sl) {
        bf16x8 paf;
        if (sl == 0)      MKFRAG(s0, 0, paf)
        else if (sl == 1) MKFRAG(s0, 8, paf)
        else if (sl == 2) MKFRAG(s1, 0, paf)
        else              MKFRAG(s1, 8, paf)
        int m0 = 8 * sl + 4 * hi;
#pragma unroll
        for (int g = 0; g < 2; ++g) {
          int d = lq + 32 * g;
          const u32* vp = vt + d * 34 + m0;
          union { u32 u[4]; bf16x8 v; } vv;
          uint2 lo = *(const uint2*)vp;
          uint2 hi2 = *(const uint2*)(vp + 2);
          vv.u[0] = lo.x; vv.u[1] = lo.y; vv.u[2] = hi2.x; vv.u[3] = hi2.y;
          if (g == 0) o0 = __builtin_amdgcn_mfma_f32_32x32x16_bf16(vv.v, paf, o0, 0, 0, 0);
          else        o1 = __builtin_amdgcn_mfma_f32_32x32x16_bf16(vv.v, paf, o1, 0, 0, 0);
        }
      }
    }
  }

  // ---- epilogue: normalize, LDS transpose, coalesced store ----
  __syncthreads();   // all waves done with K/V buffers
  ls += __shfl_xor(ls, 32);
  float inv = 1.f / ls;
  char* od = lds + w * 4096;
#pragma unroll
  for (int g = 0; g < 2; ++g) {
#pragma unroll
    for (int r = 0; r < 16; r += 2) {
      int d = (r & 3) + 8 * (r >> 2) + 4 * hi + 32 * g;
      float e0 = (g ? o1[r] : o0[r]) * inv;
      float e1 = (g ? o1[r + 1] : o0[r + 1]) * inv;
      *(u32*)(od + lq * 128 + ((d * 2) ^ ((lq & 7) << 4))) = pk2(e0, e1);
    }
  }
#pragma unroll
  for (int i = 0; i < 4; ++i) {
    int q = l >> 1;
    int c = (l & 1) * 4 + i;
    uint4 vv = *(const uint4*)(od + q * 128 + ((c * 16) ^ ((q & 7) << 4)));
    *(uint4*)(O + ((bT + q0w + q) * HN + h) * 64 + c * 8) = vv;
  }
}

extern "C" void kernel_launch(void* const* d_in, const int* in_sizes, int n_in,
                              void* d_out, int out_size, void* d_ws, size_t ws_size,
                              hipStream_t stream) {
  const float* x    = (const float*)d_in[0];
  const float* Wq   = (const float*)d_in[1];
  const float* Wk   = (const float*)d_in[2];
  const float* Wv   = (const float*)d_in[3];
  const float* Wo   = (const float*)d_in[4];
  const float* cosT = (const float*)d_in[5];
  const float* sinT = (const float*)d_in[6];

  char* ws = (char*)d_ws;
  u16* xb  = (u16*)(ws + 0);          // 16 MB
  u16* wqb = (u16*)(ws + 16777216);   //  8 MB
  u16* wkb = (u16*)(ws + 25165824);   //  2 MB
  u16* wvb = (u16*)(ws + 27262976);   //  2 MB
  u16* wob = (u16*)(ws + 29360128);   //  8 MB
  u16* qb  = (u16*)(ws + 37748736);   // 16 MB
  u16* kb  = (u16*)(ws + 54525952);   //  4 MB
  u16* vb  = (u16*)(ws + 58720256);   //  4 MB
  u16* aob = (u16*)(ws + 62914560);   // 16 MB

  cvt_f32_bf16<<<4096, 256, 0, stream>>>(x, xb, 1048576);
  cvt_f32_bf16<<<2048, 256, 0, stream>>>(Wq, wqb, 524288);
  cvt_f32_bf16<<<512, 256, 0, stream>>>(Wk, wkb, 131072);
  cvt_f32_bf16<<<512, 256, 0, stream>>>(Wv, wvb, 131072);
  cvt_f32_bf16<<<2048, 256, 0, stream>>>(Wo, wob, 524288);

  gemm_bt<u16><<<dim3(16, 32), 256, 0, stream>>>(xb, wqb, qb, 2048, 2048);
  gemm_kv<<<dim3(8, 32), 256, 0, stream>>>(xb, wkb, wvb, kb, vb, 2048);

  rope_scale<<<16384, 256, 0, stream>>>(qb, cosT, sinT, 5, 0.125f, 4194304);
  rope_scale<<<4096, 256, 0, stream>>>(kb, cosT, sinT, 3, 1.0f, 1048576);

  attn_kernel<<<dim3(16, 32, 2), 256, 0, stream>>>(qb, kb, vb, aob);

  gemm_bt<float><<<dim3(16, 32), 256, 0, stream>>>(aob, wob, (float*)d_out, 2048, 2048);
}

// Round 4
// 325.326 us; speedup vs baseline: 1.3013x; 1.0369x over previous
//
#include <hip/hip_runtime.h>
#include <hip/hip_bf16.h>
#include <type_traits>

#define T_LEN 2048
#define HN 32
#define KVHN 8

typedef unsigned short u16;
typedef unsigned int u32;
typedef __attribute__((ext_vector_type(8))) short bf16x8;
typedef __attribute__((ext_vector_type(4))) float f32x4;
typedef __attribute__((ext_vector_type(16))) float f32x16;

__device__ __forceinline__ u16 f2b(float f) {
  __hip_bfloat16 h = __float2bfloat16(f);
  return __builtin_bit_cast(u16, h);
}
__device__ __forceinline__ float b2f(u16 u) {
  return __bfloat162float(__builtin_bit_cast(__hip_bfloat16, u));
}
__device__ __forceinline__ u32 pk2(float a, float b) {
  return (u32)f2b(a) | ((u32)f2b(b) << 16);
}

__device__ __forceinline__ void gload_lds16(const void* g, void* l) {
  __builtin_amdgcn_global_load_lds(
      (const __attribute__((address_space(1))) u32*)g,
      (__attribute__((address_space(3))) u32*)l, 16, 0, 0);
}

// ---------------- fp32 -> bf16 convert (8 elems/thread) ----------------
__global__ __launch_bounds__(256) void cvt_f32_bf16(const float* __restrict__ in,
                                                    u16* __restrict__ out, int n8) {
  int i = blockIdx.x * 256 + threadIdx.x;
  if (i >= n8) return;
  float4 a = ((const float4*)in)[i * 2];
  float4 b = ((const float4*)in)[i * 2 + 1];
  union { u16 s[8]; uint4 v; } r;
  r.s[0] = f2b(a.x); r.s[1] = f2b(a.y); r.s[2] = f2b(a.z); r.s[3] = f2b(a.w);
  r.s[4] = f2b(b.x); r.s[5] = f2b(b.y); r.s[6] = f2b(b.z); r.s[7] = f2b(b.w);
  ((uint4*)out)[i] = r.v;
}

// ---------------- m97-structure bf16 GEMM: C = A @ Bt^T ----------------
// MODE: 0 = bf16 out, 1 = f32 out, 2 = bf16 out + RoPE (cos/sin/mul fused)
template <int MODE>
__device__ __forceinline__ void gemm_bt_core(const u16* __restrict__ A,
                                             const u16* __restrict__ Bt,
                                             void* __restrict__ Cv,
                                             const float* __restrict__ cosT,
                                             const float* __restrict__ sinT, float mul,
                                             int brow, int bcol, int N, int K,
                                             u16* As, u16* Bs) {
  int tid = threadIdx.x;
  int w = tid >> 6, l = tid & 63;
  int wr = w >> 1, wc = w & 1;
  int lr = tid >> 2, lc = (tid & 3) * 8;
  f32x4 acc[4][4] = {};
  for (int k0 = 0; k0 < K; k0 += 32) {
    __syncthreads();
#pragma unroll
    for (int i = 0; i < 2; ++i) {
      gload_lds16(A + (size_t)(brow + i * 64 + lr) * K + k0 + lc,
                  (char*)As + i * 4096 + w * 1024);
      gload_lds16(Bt + (size_t)(bcol + i * 64 + lr) * K + k0 + lc,
                  (char*)Bs + i * 4096 + w * 1024);
    }
    __syncthreads();
    bf16x8 af[4], bfr[4];
#pragma unroll
    for (int m = 0; m < 4; ++m)
      af[m] = *(const bf16x8*)((const char*)As + (wr * 64 + m * 16 + (l & 15)) * 64 + (l >> 4) * 16);
#pragma unroll
    for (int n = 0; n < 4; ++n)
      bfr[n] = *(const bf16x8*)((const char*)Bs + (wc * 64 + n * 16 + (l & 15)) * 64 + (l >> 4) * 16);
#pragma unroll
    for (int m = 0; m < 4; ++m)
#pragma unroll
      for (int n = 0; n < 4; ++n)
        acc[m][n] = __builtin_amdgcn_mfma_f32_16x16x32_bf16(af[m], bfr[n], acc[m][n], 0, 0, 0);
  }
  if constexpr (MODE == 2) {
    u16* C = (u16*)Cv;
#pragma unroll
    for (int m = 0; m < 4; ++m)
#pragma unroll
      for (int n = 0; n < 2; ++n)
#pragma unroll
        for (int r = 0; r < 4; ++r) {
          int row = brow + wr * 64 + m * 16 + (l >> 4) * 4 + r;
          int t = row & (T_LEN - 1);
          int dlo = n * 16 + (l & 15);
          float c = cosT[t * 64 + dlo];
          float s = sinT[t * 64 + dlo];
          float lo = acc[m][n][r], hh = acc[m][n + 2][r];
          size_t base = (size_t)row * N + bcol + wc * 64 + n * 16 + (l & 15);
          C[base]      = f2b((lo * c - hh * s) * mul);
          C[base + 32] = f2b((hh * c + lo * s) * mul);
        }
  } else {
#pragma unroll
    for (int m = 0; m < 4; ++m)
#pragma unroll
      for (int n = 0; n < 4; ++n)
#pragma unroll
        for (int r = 0; r < 4; ++r) {
          size_t row = brow + wr * 64 + m * 16 + (l >> 4) * 4 + r;
          size_t col = bcol + wc * 64 + n * 16 + (l & 15);
          if constexpr (MODE == 1)
            ((float*)Cv)[row * N + col] = acc[m][n][r];
          else
            ((u16*)Cv)[row * N + col] = f2b(acc[m][n][r]);
        }
  }
}

template <int MODE>
__global__ __launch_bounds__(256) void gemm_bt(const u16* __restrict__ A,
                                               const u16* __restrict__ Bt,
                                               void* __restrict__ C,
                                               const float* __restrict__ cosT,
                                               const float* __restrict__ sinT,
                                               float mul, int N, int K) {
  __shared__ u16 As[128 * 32];
  __shared__ u16 Bs[128 * 32];
  gemm_bt_core<MODE>(A, Bt, C, cosT, sinT, mul, blockIdx.y * 128, blockIdx.x * 128, N, K, As, Bs);
}

// fused K (rope) and V projection; grid.x 0..7: 0-3 -> K, 4-7 -> V
__global__ __launch_bounds__(256) void gemm_kv(const u16* __restrict__ A,
                                               const u16* __restrict__ Wk,
                                               const u16* __restrict__ Wv,
                                               u16* __restrict__ Ko,
                                               u16* __restrict__ Vo,
                                               const float* __restrict__ cosT,
                                               const float* __restrict__ sinT, int K) {
  __shared__ u16 As[128 * 32];
  __shared__ u16 Bs[128 * 32];
  int x = blockIdx.x;
  if (x < 4)
    gemm_bt_core<2>(A, Wk, Ko, cosT, sinT, 1.0f, blockIdx.y * 128, x * 128, 512, K, As, Bs);
  else
    gemm_bt_core<0>(A, Wv, Vo, nullptr, nullptr, 0.f, blockIdx.y * 128, (x - 4) * 128, 512, K, As, Bs);
}

// ---------------- causal flash attention, 32x32 swapped-QK^T ----------------
// EXACT round-2 kernel (proven correct). Q (rope'd, pre-scaled 1/8), K (rope'd),
// V: (B,T,*,64) bf16. O: (B,T,HN,64) bf16.
// grid = (T/128, HN, B), 256 threads = 4 waves x 32 q-rows.
#define MKFRAG(SS, RB, OUTV)                                              \
  {                                                                       \
    u32 a_ = pk2(SS[RB + 0], SS[RB + 1]);                                 \
    u32 b_ = pk2(SS[RB + 4], SS[RB + 5]);                                 \
    u32 c_ = pk2(SS[RB + 2], SS[RB + 3]);                                 \
    u32 d_ = pk2(SS[RB + 6], SS[RB + 7]);                                 \
    asm volatile("v_permlane32_swap_b32 %0, %1" : "+v"(a_), "+v"(b_));    \
    asm volatile("v_permlane32_swap_b32 %0, %1" : "+v"(c_), "+v"(d_));    \
    union { u32 u[4]; bf16x8 v; } r_;                                     \
    r_.u[0] = a_; r_.u[1] = c_; r_.u[2] = b_; r_.u[3] = d_;               \
    OUTV = r_.v;                                                          \
  }

__global__ __launch_bounds__(256, 3) void attn_kernel(const u16* __restrict__ Q,
                                                      const u16* __restrict__ K,
                                                      const u16* __restrict__ V,
                                                      u16* __restrict__ O) {
  const float L2E = 1.4426950408889634f;
  int qi = blockIdx.x, h = blockIdx.y, b = blockIdx.z;
  int kvh = h >> 2;
  int tid = threadIdx.x;
  int w = tid >> 6, l = tid & 63;
  int lq = l & 31;
  int hi = l >> 5;
  int q0blk = qi * 128;
  int q0w = q0blk + w * 32;
  int nt = 2 * qi + 2;
  const size_t bT = (size_t)b * T_LEN;

  __shared__ char lds[33792];

  // ---- stage Q (swizzled source), read frags, free the region ----
#pragma unroll
  for (int i = 0; i < 4; ++i) {
    int u = (i * 4 + w) * 64 + l;
    int row = u >> 3, blk = (u & 7) ^ (row & 7);
    gload_lds16(Q + ((bT + q0blk + row) * HN + h) * 64 + blk * 8,
                lds + (i * 4 + w) * 1024);
  }
  __syncthreads();
  bf16x8 qf[4];
  {
    int R = w * 32 + lq;
#pragma unroll
    for (int ks = 0; ks < 4; ++ks) {
      int kb = 2 * ks + hi;
      qf[ks] = *(const bf16x8*)(lds + R * 128 + ((kb ^ (R & 7)) * 16));
    }
  }
  __syncthreads();

  // ---- V reg-stage state ----
  int r2 = tid >> 3;            // kv-pair 0..31
  int d0v = (tid & 7) * 8;      // d chunk
  uint4 va, vb;

  // ---- stage tile 0 ----
  {
#pragma unroll
    for (int i = 0; i < 2; ++i) {
      int u = (w * 2 + i) * 64 + l;
      int row = u >> 3, blk = (u & 7) ^ (row & 7);
      gload_lds16(K + ((bT + row) * KVHN + kvh) * 64 + blk * 8,
                  lds + (w * 2 + i) * 1024);
    }
    const u16* g0 = V + ((bT + 2 * r2) * KVHN + kvh) * 64 + d0v;
    va = *(const uint4*)g0;
    vb = *(const uint4*)(g0 + KVHN * 64);
    u32* vt = (u32*)(lds + 16384);
    const u16* pa = (const u16*)&va;
    const u16* pb = (const u16*)&vb;
#pragma unroll
    for (int j = 0; j < 8; ++j)
      vt[(d0v + j) * 34 + r2] = (u32)pa[j] | ((u32)pb[j] << 16);
  }

  f32x16 o0 = {}, o1 = {};
  float mx = -1e30f, ls = 0.f;

  for (int t = 0; t < nt; ++t) {
    __syncthreads();   // staging of buf[t&1] complete; buf[t&1^1] free
    int cur = t & 1, nxt = cur ^ 1;
    bool last = (t + 1 >= nt);
    int kv0 = t * 64;
    bool skip = kv0 > q0w + 31;

    // issue next-tile staging (overlaps with this tile's compute)
    if (!last) {
      int kvn = kv0 + 64;
#pragma unroll
      for (int i = 0; i < 2; ++i) {
        int u = (w * 2 + i) * 64 + l;
        int row = u >> 3, blk = (u & 7) ^ (row & 7);
        gload_lds16(K + ((bT + kvn + row) * KVHN + kvh) * 64 + blk * 8,
                    lds + nxt * 8192 + (w * 2 + i) * 1024);
      }
      const u16* g0 = V + ((bT + kvn + 2 * r2) * KVHN + kvh) * 64 + d0v;
      va = *(const uint4*)g0;
      vb = *(const uint4*)(g0 + KVHN * 64);
    }

    f32x16 s0 = {}, s1 = {};
    if (!skip) {
      const char* kb = lds + cur * 8192;
#pragma unroll
      for (int ks = 0; ks < 4; ++ks) {
        int kbi = 2 * ks + hi;
        int R0 = lq, R1 = 32 + lq;
        bf16x8 k0 = *(const bf16x8*)(kb + R0 * 128 + ((kbi ^ (R0 & 7)) * 16));
        bf16x8 k1 = *(const bf16x8*)(kb + R1 * 128 + ((kbi ^ (R1 & 7)) * 16));
        s0 = __builtin_amdgcn_mfma_f32_32x32x16_bf16(k0, qf[ks], s0, 0, 0, 0);
        s1 = __builtin_amdgcn_mfma_f32_32x32x16_bf16(k1, qf[ks], s1, 0, 0, 0);
      }
      if (kv0 + 63 > q0w) {   // partial tile: causal mask
        int qa = q0w + lq;
#pragma unroll
        for (int r = 0; r < 16; ++r) {
          int kvl = (r & 3) + 8 * (r >> 2) + 4 * hi;
          if (kv0 + kvl > qa) s0[r] = -1e30f;
          if (kv0 + 32 + kvl > qa) s1[r] = -1e30f;
        }
      }
      // online softmax (q = lane&31; kv split across hi-halves)
      float rm = s0[0];
#pragma unroll
      for (int r = 1; r < 16; ++r) rm = fmaxf(rm, s0[r]);
#pragma unroll
      for (int r = 0; r < 16; ++r) rm = fmaxf(rm, s1[r]);
      rm = fmaxf(rm, __shfl_xor(rm, 32));
      float nm = mx;
      if (!__all(rm <= mx + 8.0f)) {   // defer-max (T13)
        nm = fmaxf(mx, rm);
        float fac = exp2f((mx - nm) * L2E);
        mx = nm;
        ls *= fac;
#pragma unroll
        for (int r = 0; r < 16; ++r) { o0[r] *= fac; o1[r] *= fac; }
      }
      float psum = 0.f;
#pragma unroll
      for (int r = 0; r < 16; ++r) { float p = exp2f((s0[r] - nm) * L2E); s0[r] = p; psum += p; }
#pragma unroll
      for (int r = 0; r < 16; ++r) { float p = exp2f((s1[r] - nm) * L2E); s1[r] = p; psum += p; }
      ls += psum;
    }

    // write next-tile V (pair-packed transpose) into the other buffer
    if (!last) {
      u32* vt = (u32*)(lds + 16384 + nxt * 8704);
      const u16* pa = (const u16*)&va;
      const u16* pb = (const u16*)&vb;
#pragma unroll
      for (int j = 0; j < 8; ++j)
        vt[(d0v + j) * 34 + r2] = (u32)pa[j] | ((u32)pb[j] << 16);
    }

    if (!skip) {
      // P fragments (B-operand, in-register via pack+permlane) + PV
      const u32* vt = (const u32*)(lds + 16384 + cur * 8704);
#pragma unroll
      for (int sl = 0; sl < 4; ++sl) {
        bf16x8 paf;
        if (sl == 0)      MKFRAG(s0, 0, paf)
        else if (sl == 1) MKFRAG(s0, 8, paf)
        else if (sl == 2) MKFRAG(s1, 0, paf)
        else              MKFRAG(s1, 8, paf)
        int m0 = 8 * sl + 4 * hi;
#pragma unroll
        for (int g = 0; g < 2; ++g) {
          int d = lq + 32 * g;
          const u32* vp = vt + d * 34 + m0;
          union { u32 u[4]; bf16x8 v; } vv;
          uint2 lo = *(const uint2*)vp;
          uint2 hi2 = *(const uint2*)(vp + 2);
          vv.u[0] = lo.x; vv.u[1] = lo.y; vv.u[2] = hi2.x; vv.u[3] = hi2.y;
          if (g == 0) o0 = __builtin_amdgcn_mfma_f32_32x32x16_bf16(vv.v, paf, o0, 0, 0, 0);
          else        o1 = __builtin_amdgcn_mfma_f32_32x32x16_bf16(vv.v, paf, o1, 0, 0, 0);
        }
      }
    }
  }

  // ---- epilogue: normalize, LDS transpose, coalesced store ----
  __syncthreads();   // all waves done with K/V buffers
  ls += __shfl_xor(ls, 32);
  float inv = 1.f / ls;
  char* od = lds + w * 4096;
#pragma unroll
  for (int g = 0; g < 2; ++g) {
#pragma unroll
    for (int r = 0; r < 16; r += 2) {
      int d = (r & 3) + 8 * (r >> 2) + 4 * hi + 32 * g;
      float e0 = (g ? o1[r] : o0[r]) * inv;
      float e1 = (g ? o1[r + 1] : o0[r + 1]) * inv;
      *(u32*)(od + lq * 128 + ((d * 2) ^ ((lq & 7) << 4))) = pk2(e0, e1);
    }
  }
  __syncthreads();
#pragma unroll
  for (int i = 0; i < 4; ++i) {
    int q = l >> 1;
    int c = (l & 1) * 4 + i;
    uint4 vv = *(const uint4*)(od + q * 128 + ((c * 16) ^ ((q & 7) << 4)));
    *(uint4*)(O + ((bT + q0w + q) * HN + h) * 64 + c * 8) = vv;
  }
}

extern "C" void kernel_launch(void* const* d_in, const int* in_sizes, int n_in,
                              void* d_out, int out_size, void* d_ws, size_t ws_size,
                              hipStream_t stream) {
  const float* x    = (const float*)d_in[0];
  const float* Wq   = (const float*)d_in[1];
  const float* Wk   = (const float*)d_in[2];
  const float* Wv   = (const float*)d_in[3];
  const float* Wo   = (const float*)d_in[4];
  const float* cosT = (const float*)d_in[5];
  const float* sinT = (const float*)d_in[6];

  char* ws = (char*)d_ws;
  u16* xb  = (u16*)(ws + 0);          // 16 MB
  u16* wqb = (u16*)(ws + 16777216);   //  8 MB
  u16* wkb = (u16*)(ws + 25165824);   //  2 MB
  u16* wvb = (u16*)(ws + 27262976);   //  2 MB
  u16* wob = (u16*)(ws + 29360128);   //  8 MB
  u16* qb  = (u16*)(ws + 37748736);   // 16 MB
  u16* kb  = (u16*)(ws + 54525952);   //  4 MB
  u16* vb  = (u16*)(ws + 58720256);   //  4 MB
  u16* aob = (u16*)(ws + 62914560);   // 16 MB

  cvt_f32_bf16<<<4096, 256, 0, stream>>>(x, xb, 1048576);
  cvt_f32_bf16<<<2048, 256, 0, stream>>>(Wq, wqb, 524288);
  cvt_f32_bf16<<<512, 256, 0, stream>>>(Wk, wkb, 131072);
  cvt_f32_bf16<<<512, 256, 0, stream>>>(Wv, wvb, 131072);
  cvt_f32_bf16<<<2048, 256, 0, stream>>>(Wo, wob, 524288);

  gemm_bt<2><<<dim3(16, 32), 256, 0, stream>>>(xb, wqb, qb, cosT, sinT, 0.125f, 2048, 2048);
  gemm_kv<<<dim3(8, 32), 256, 0, stream>>>(xb, wkb, wvb, kb, vb, cosT, sinT, 2048);

  attn_kernel<<<dim3(16, 32, 2), 256, 0, stream>>>(qb, kb, vb, aob);

  gemm_bt<1><<<dim3(16, 32), 256, 0, stream>>>(aob, wob, d_out, nullptr, nullptr, 0.f, 2048, 2048);
}

// Round 5
// 271.891 us; speedup vs baseline: 1.5571x; 1.1965x over previous
//
#include <hip/hip_runtime.h>
#include <hip/hip_bf16.h>
#include <type_traits>

#define T_LEN 2048
#define HN 32
#define KVHN 8

typedef unsigned short u16;
typedef unsigned int u32;
typedef __attribute__((ext_vector_type(8))) short bf16x8;
typedef __attribute__((ext_vector_type(4))) float f32x4;
typedef __attribute__((ext_vector_type(16))) float f32x16;

__device__ __forceinline__ u16 f2b(float f) {
  __hip_bfloat16 h = __float2bfloat16(f);
  return __builtin_bit_cast(u16, h);
}
__device__ __forceinline__ float b2f(u16 u) {
  return __bfloat162float(__builtin_bit_cast(__hip_bfloat16, u));
}
__device__ __forceinline__ u32 pk2(float a, float b) {
  return (u32)f2b(a) | ((u32)f2b(b) << 16);
}
// raw v_exp_f32: exact exp2, no libm denormal fixup. Inputs here are in
// (-inf, +8*log2e]; FTZ on the huge-negative masked values is desired.
__device__ __forceinline__ float fexp2(float x) {
  float r;
  asm("v_exp_f32 %0, %1" : "=v"(r) : "v"(x));
  return r;
}

__device__ __forceinline__ void gload_lds16(const void* g, void* l) {
  __builtin_amdgcn_global_load_lds(
      (const __attribute__((address_space(1))) u32*)g,
      (__attribute__((address_space(3))) u32*)l, 16, 0, 0);
}

// ---------------- fp32 -> bf16 convert (8 elems/thread) ----------------
__global__ __launch_bounds__(256) void cvt_f32_bf16(const float* __restrict__ in,
                                                    u16* __restrict__ out, int n8) {
  int i = blockIdx.x * 256 + threadIdx.x;
  if (i >= n8) return;
  float4 a = ((const float4*)in)[i * 2];
  float4 b = ((const float4*)in)[i * 2 + 1];
  union { u16 s[8]; uint4 v; } r;
  r.s[0] = f2b(a.x); r.s[1] = f2b(a.y); r.s[2] = f2b(a.z); r.s[3] = f2b(a.w);
  r.s[4] = f2b(b.x); r.s[5] = f2b(b.y); r.s[6] = f2b(b.z); r.s[7] = f2b(b.w);
  ((uint4*)out)[i] = r.v;
}

// ---------------- m97-structure bf16 GEMM: C = A @ Bt^T ----------------
// MODE: 0 = bf16 out, 1 = f32 out, 2 = bf16 out + RoPE (cos/sin/mul fused)
template <int MODE>
__device__ __forceinline__ void gemm_bt_core(const u16* __restrict__ A,
                                             const u16* __restrict__ Bt,
                                             void* __restrict__ Cv,
                                             const float* __restrict__ cosT,
                                             const float* __restrict__ sinT, float mul,
                                             int brow, int bcol, int N, int K,
                                             u16* As, u16* Bs) {
  int tid = threadIdx.x;
  int w = tid >> 6, l = tid & 63;
  int wr = w >> 1, wc = w & 1;
  int lr = tid >> 2, lc = (tid & 3) * 8;
  f32x4 acc[4][4] = {};
  for (int k0 = 0; k0 < K; k0 += 32) {
    __syncthreads();
#pragma unroll
    for (int i = 0; i < 2; ++i) {
      gload_lds16(A + (size_t)(brow + i * 64 + lr) * K + k0 + lc,
                  (char*)As + i * 4096 + w * 1024);
      gload_lds16(Bt + (size_t)(bcol + i * 64 + lr) * K + k0 + lc,
                  (char*)Bs + i * 4096 + w * 1024);
    }
    __syncthreads();
    bf16x8 af[4], bfr[4];
#pragma unroll
    for (int m = 0; m < 4; ++m)
      af[m] = *(const bf16x8*)((const char*)As + (wr * 64 + m * 16 + (l & 15)) * 64 + (l >> 4) * 16);
#pragma unroll
    for (int n = 0; n < 4; ++n)
      bfr[n] = *(const bf16x8*)((const char*)Bs + (wc * 64 + n * 16 + (l & 15)) * 64 + (l >> 4) * 16);
#pragma unroll
    for (int m = 0; m < 4; ++m)
#pragma unroll
      for (int n = 0; n < 4; ++n)
        acc[m][n] = __builtin_amdgcn_mfma_f32_16x16x32_bf16(af[m], bfr[n], acc[m][n], 0, 0, 0);
  }
  if constexpr (MODE == 2) {
    u16* C = (u16*)Cv;
#pragma unroll
    for (int m = 0; m < 4; ++m)
#pragma unroll
      for (int n = 0; n < 2; ++n)
#pragma unroll
        for (int r = 0; r < 4; ++r) {
          int row = brow + wr * 64 + m * 16 + (l >> 4) * 4 + r;
          int t = row & (T_LEN - 1);
          int dlo = n * 16 + (l & 15);
          float c = cosT[t * 64 + dlo];
          float s = sinT[t * 64 + dlo];
          float lo = acc[m][n][r], hh = acc[m][n + 2][r];
          size_t base = (size_t)row * N + bcol + wc * 64 + n * 16 + (l & 15);
          C[base]      = f2b((lo * c - hh * s) * mul);
          C[base + 32] = f2b((hh * c + lo * s) * mul);
        }
  } else {
#pragma unroll
    for (int m = 0; m < 4; ++m)
#pragma unroll
      for (int n = 0; n < 4; ++n)
#pragma unroll
        for (int r = 0; r < 4; ++r) {
          size_t row = brow + wr * 64 + m * 16 + (l >> 4) * 4 + r;
          size_t col = bcol + wc * 64 + n * 16 + (l & 15);
          if constexpr (MODE == 1)
            ((float*)Cv)[row * N + col] = acc[m][n][r];
          else
            ((u16*)Cv)[row * N + col] = f2b(acc[m][n][r]);
        }
  }
}

template <int MODE>
__global__ __launch_bounds__(256) void gemm_bt(const u16* __restrict__ A,
                                               const u16* __restrict__ Bt,
                                               void* __restrict__ C,
                                               const float* __restrict__ cosT,
                                               const float* __restrict__ sinT,
                                               float mul, int N, int K) {
  __shared__ u16 As[128 * 32];
  __shared__ u16 Bs[128 * 32];
  gemm_bt_core<MODE>(A, Bt, C, cosT, sinT, mul, blockIdx.y * 128, blockIdx.x * 128, N, K, As, Bs);
}

// fused K (rope) and V projection; grid.x 0..7: 0-3 -> K, 4-7 -> V
__global__ __launch_bounds__(256) void gemm_kv(const u16* __restrict__ A,
                                               const u16* __restrict__ Wk,
                                               const u16* __restrict__ Wv,
                                               u16* __restrict__ Ko,
                                               u16* __restrict__ Vo,
                                               const float* __restrict__ cosT,
                                               const float* __restrict__ sinT, int K) {
  __shared__ u16 As[128 * 32];
  __shared__ u16 Bs[128 * 32];
  int x = blockIdx.x;
  if (x < 4)
    gemm_bt_core<2>(A, Wk, Ko, cosT, sinT, 1.0f, blockIdx.y * 128, x * 128, 512, K, As, Bs);
  else
    gemm_bt_core<0>(A, Wv, Vo, nullptr, nullptr, 0.f, blockIdx.y * 128, (x - 4) * 128, 512, K, As, Bs);
}

// ---------------- causal flash attention, 32x32 swapped-QK^T ----------------
// Proven round-2 body as a function of qi; block runs it for qi=qp and qi=15-qp
// sequentially (uniform 34 tiles/block -> no causal tail). fexp2 + setprio added.
#define MKFRAG(SS, RB, OUTV)                                              \
  {                                                                       \
    u32 a_ = pk2(SS[RB + 0], SS[RB + 1]);                                 \
    u32 b_ = pk2(SS[RB + 4], SS[RB + 5]);                                 \
    u32 c_ = pk2(SS[RB + 2], SS[RB + 3]);                                 \
    u32 d_ = pk2(SS[RB + 6], SS[RB + 7]);                                 \
    asm volatile("v_permlane32_swap_b32 %0, %1" : "+v"(a_), "+v"(b_));    \
    asm volatile("v_permlane32_swap_b32 %0, %1" : "+v"(c_), "+v"(d_));    \
    union { u32 u[4]; bf16x8 v; } r_;                                     \
    r_.u[0] = a_; r_.u[1] = c_; r_.u[2] = b_; r_.u[3] = d_;               \
    OUTV = r_.v;                                                          \
  }

__device__ void attn_one(int qi, int h, int kvh, size_t bT,
                         const u16* __restrict__ Q, const u16* __restrict__ K,
                         const u16* __restrict__ V, u16* __restrict__ O,
                         char* lds) {
  const float L2E = 1.4426950408889634f;
  int tid = threadIdx.x;
  int w = tid >> 6, l = tid & 63;
  int lq = l & 31;
  int hi = l >> 5;
  int q0blk = qi * 128;
  int q0w = q0blk + w * 32;
  int nt = 2 * qi + 2;

  // ---- stage Q (swizzled source), read frags, free the region ----
#pragma unroll
  for (int i = 0; i < 4; ++i) {
    int u = (i * 4 + w) * 64 + l;
    int row = u >> 3, blk = (u & 7) ^ (row & 7);
    gload_lds16(Q + ((bT + q0blk + row) * HN + h) * 64 + blk * 8,
                lds + (i * 4 + w) * 1024);
  }
  __syncthreads();
  bf16x8 qf[4];
  {
    int R = w * 32 + lq;
#pragma unroll
    for (int ks = 0; ks < 4; ++ks) {
      int kb = 2 * ks + hi;
      qf[ks] = *(const bf16x8*)(lds + R * 128 + ((kb ^ (R & 7)) * 16));
    }
  }
  __syncthreads();

  // ---- V reg-stage state ----
  int r2 = tid >> 3;            // kv-pair 0..31
  int d0v = (tid & 7) * 8;      // d chunk
  uint4 va, vb;

  // ---- stage tile 0 ----
  {
#pragma unroll
    for (int i = 0; i < 2; ++i) {
      int u = (w * 2 + i) * 64 + l;
      int row = u >> 3, blk = (u & 7) ^ (row & 7);
      gload_lds16(K + ((bT + row) * KVHN + kvh) * 64 + blk * 8,
                  lds + (w * 2 + i) * 1024);
    }
    const u16* g0 = V + ((bT + 2 * r2) * KVHN + kvh) * 64 + d0v;
    va = *(const uint4*)g0;
    vb = *(const uint4*)(g0 + KVHN * 64);
    u32* vt = (u32*)(lds + 16384);
    const u16* pa = (const u16*)&va;
    const u16* pb = (const u16*)&vb;
#pragma unroll
    for (int j = 0; j < 8; ++j)
      vt[(d0v + j) * 34 + r2] = (u32)pa[j] | ((u32)pb[j] << 16);
  }

  f32x16 o0 = {}, o1 = {};
  float mx = -1e30f, ls = 0.f;

  for (int t = 0; t < nt; ++t) {
    __syncthreads();   // staging of buf[t&1] complete; buf[t&1^1] free
    int cur = t & 1, nxt = cur ^ 1;
    bool last = (t + 1 >= nt);
    int kv0 = t * 64;
    bool skip = kv0 > q0w + 31;

    // issue next-tile staging (overlaps with this tile's compute)
    if (!last) {
      int kvn = kv0 + 64;
#pragma unroll
      for (int i = 0; i < 2; ++i) {
        int u = (w * 2 + i) * 64 + l;
        int row = u >> 3, blk = (u & 7) ^ (row & 7);
        gload_lds16(K + ((bT + kvn + row) * KVHN + kvh) * 64 + blk * 8,
                    lds + nxt * 8192 + (w * 2 + i) * 1024);
      }
      const u16* g0 = V + ((bT + kvn + 2 * r2) * KVHN + kvh) * 64 + d0v;
      va = *(const uint4*)g0;
      vb = *(const uint4*)(g0 + KVHN * 64);
    }

    f32x16 s0 = {}, s1 = {};
    if (!skip) {
      const char* kb = lds + cur * 8192;
      __builtin_amdgcn_s_setprio(1);
#pragma unroll
      for (int ks = 0; ks < 4; ++ks) {
        int kbi = 2 * ks + hi;
        int R0 = lq, R1 = 32 + lq;
        bf16x8 k0 = *(const bf16x8*)(kb + R0 * 128 + ((kbi ^ (R0 & 7)) * 16));
        bf16x8 k1 = *(const bf16x8*)(kb + R1 * 128 + ((kbi ^ (R1 & 7)) * 16));
        s0 = __builtin_amdgcn_mfma_f32_32x32x16_bf16(k0, qf[ks], s0, 0, 0, 0);
        s1 = __builtin_amdgcn_mfma_f32_32x32x16_bf16(k1, qf[ks], s1, 0, 0, 0);
      }
      __builtin_amdgcn_s_setprio(0);
      if (kv0 + 63 > q0w) {   // partial tile: causal mask
        int qa = q0w + lq;
#pragma unroll
        for (int r = 0; r < 16; ++r) {
          int kvl = (r & 3) + 8 * (r >> 2) + 4 * hi;
          if (kv0 + kvl > qa) s0[r] = -1e30f;
          if (kv0 + 32 + kvl > qa) s1[r] = -1e30f;
        }
      }
      // online softmax (q = lane&31; kv split across hi-halves)
      float rm = s0[0];
#pragma unroll
      for (int r = 1; r < 16; ++r) rm = fmaxf(rm, s0[r]);
#pragma unroll
      for (int r = 0; r < 16; ++r) rm = fmaxf(rm, s1[r]);
      rm = fmaxf(rm, __shfl_xor(rm, 32));
      float nm = mx;
      if (!__all(rm <= mx + 8.0f)) {   // defer-max (T13)
        nm = fmaxf(mx, rm);
        float fac = fexp2((mx - nm) * L2E);
        mx = nm;
        ls *= fac;
#pragma unroll
        for (int r = 0; r < 16; ++r) { o0[r] *= fac; o1[r] *= fac; }
      }
      float psum = 0.f;
#pragma unroll
      for (int r = 0; r < 16; ++r) { float p = fexp2((s0[r] - nm) * L2E); s0[r] = p; psum += p; }
#pragma unroll
      for (int r = 0; r < 16; ++r) { float p = fexp2((s1[r] - nm) * L2E); s1[r] = p; psum += p; }
      ls += psum;
    }

    // write next-tile V (pair-packed transpose) into the other buffer
    if (!last) {
      u32* vt = (u32*)(lds + 16384 + nxt * 8704);
      const u16* pa = (const u16*)&va;
      const u16* pb = (const u16*)&vb;
#pragma unroll
      for (int j = 0; j < 8; ++j)
        vt[(d0v + j) * 34 + r2] = (u32)pa[j] | ((u32)pb[j] << 16);
    }

    if (!skip) {
      // P fragments (B-operand, in-register via pack+permlane) + PV
      const u32* vt = (const u32*)(lds + 16384 + cur * 8704);
#pragma unroll
      for (int sl = 0; sl < 4; ++sl) {
        bf16x8 paf;
        if (sl == 0)      MKFRAG(s0, 0, paf)
        else if (sl == 1) MKFRAG(s0, 8, paf)
        else if (sl == 2) MKFRAG(s1, 0, paf)
        else              MKFRAG(s1, 8, paf)
        int m0 = 8 * sl + 4 * hi;
        __builtin_amdgcn_s_setprio(1);
#pragma unroll
        for (int g = 0; g < 2; ++g) {
          int d = lq + 32 * g;
          const u32* vp = vt + d * 34 + m0;
          union { u32 u[4]; bf16x8 v; } vv;
          uint2 lo = *(const uint2*)vp;
          uint2 hi2 = *(const uint2*)(vp + 2);
          vv.u[0] = lo.x; vv.u[1] = lo.y; vv.u[2] = hi2.x; vv.u[3] = hi2.y;
          if (g == 0) o0 = __builtin_amdgcn_mfma_f32_32x32x16_bf16(vv.v, paf, o0, 0, 0, 0);
          else        o1 = __builtin_amdgcn_mfma_f32_32x32x16_bf16(vv.v, paf, o1, 0, 0, 0);
        }
        __builtin_amdgcn_s_setprio(0);
      }
    }
  }

  // ---- epilogue: normalize, LDS transpose, coalesced store ----
  __syncthreads();   // all waves done with K/V buffers
  ls += __shfl_xor(ls, 32);
  float inv = 1.f / ls;
  char* od = lds + w * 4096;
#pragma unroll
  for (int g = 0; g < 2; ++g) {
#pragma unroll
    for (int r = 0; r < 16; r += 2) {
      int d = (r & 3) + 8 * (r >> 2) + 4 * hi + 32 * g;
      float e0 = (g ? o1[r] : o0[r]) * inv;
      float e1 = (g ? o1[r + 1] : o0[r + 1]) * inv;
      *(u32*)(od + lq * 128 + ((d * 2) ^ ((lq & 7) << 4))) = pk2(e0, e1);
    }
  }
  __syncthreads();
#pragma unroll
  for (int i = 0; i < 4; ++i) {
    int q = l >> 1;
    int c = (l & 1) * 4 + i;
    uint4 vv = *(const uint4*)(od + q * 128 + ((c * 16) ^ ((q & 7) << 4)));
    *(uint4*)(O + ((bT + q0w + q) * HN + h) * 64 + c * 8) = vv;
  }
}

__global__ __launch_bounds__(256, 3) void attn_kernel(const u16* __restrict__ Q,
                                                      const u16* __restrict__ K,
                                                      const u16* __restrict__ V,
                                                      u16* __restrict__ O) {
  int qp = blockIdx.x, h = blockIdx.y, b = blockIdx.z;
  int kvh = h >> 2;
  const size_t bT = (size_t)b * T_LEN;
  __shared__ char lds[33792];

  attn_one(qp, h, kvh, bT, Q, K, V, O, lds);        // 2*qp+2 tiles
  __syncthreads();                                   // epilogue reads done before re-stage
  attn_one(15 - qp, h, kvh, bT, Q, K, V, O, lds);    // 32-2*qp tiles  (sum = 34)
}

extern "C" void kernel_launch(void* const* d_in, const int* in_sizes, int n_in,
                              void* d_out, int out_size, void* d_ws, size_t ws_size,
                              hipStream_t stream) {
  const float* x    = (const float*)d_in[0];
  const float* Wq   = (const float*)d_in[1];
  const float* Wk   = (const float*)d_in[2];
  const float* Wv   = (const float*)d_in[3];
  const float* Wo   = (const float*)d_in[4];
  const float* cosT = (const float*)d_in[5];
  const float* sinT = (const float*)d_in[6];

  char* ws = (char*)d_ws;
  u16* xb  = (u16*)(ws + 0);          // 16 MB
  u16* wqb = (u16*)(ws + 16777216);   //  8 MB
  u16* wkb = (u16*)(ws + 25165824);   //  2 MB
  u16* wvb = (u16*)(ws + 27262976);   //  2 MB
  u16* wob = (u16*)(ws + 29360128);   //  8 MB
  u16* qb  = (u16*)(ws + 37748736);   // 16 MB
  u16* kb  = (u16*)(ws + 54525952);   //  4 MB
  u16* vb  = (u16*)(ws + 58720256);   //  4 MB
  u16* aob = (u16*)(ws + 62914560);   // 16 MB

  cvt_f32_bf16<<<4096, 256, 0, stream>>>(x, xb, 1048576);
  cvt_f32_bf16<<<2048, 256, 0, stream>>>(Wq, wqb, 524288);
  cvt_f32_bf16<<<512, 256, 0, stream>>>(Wk, wkb, 131072);
  cvt_f32_bf16<<<512, 256, 0, stream>>>(Wv, wvb, 131072);
  cvt_f32_bf16<<<2048, 256, 0, stream>>>(Wo, wob, 524288);

  gemm_bt<2><<<dim3(16, 32), 256, 0, stream>>>(xb, wqb, qb, cosT, sinT, 0.125f, 2048, 2048);
  gemm_kv<<<dim3(8, 32), 256, 0, stream>>>(xb, wkb, wvb, kb, vb, cosT, sinT, 2048);

  attn_kernel<<<dim3(8, 32, 2), 256, 0, stream>>>(qb, kb, vb, aob);

  gemm_bt<1><<<dim3(16, 32), 256, 0, stream>>>(aob, wob, d_out, nullptr, nullptr, 0.f, 2048, 2048);
}